// Round 2
// baseline (181.656 us; speedup 1.0000x reference)
//
#include <hip/hip_runtime.h>
#include <stdint.h>
#include <stddef.h>

// Problem constants
#define HOUT 64
#define WOUT 64
#define CIN  32
#define COUT 16
#define BATCH 64
#define SLOC 4096          // HOUT*WOUT
#define KTOT 288           // CIN*9
#define HPAD 66            // 64 + 2 pad
// Padded-X pixel block = BATCH*CIN bf16 = 2048 ushorts = 4096 bytes

typedef __attribute__((ext_vector_type(8))) short  short8;   // 8 bf16 (4 VGPRs)
typedef __attribute__((ext_vector_type(4))) float  floatx4;  // MFMA acc / float4

// fp32 -> bf16 round-to-nearest-even (bit pattern)
static __device__ __forceinline__ unsigned short f2bf(float f) {
    union { float f; unsigned int u; } v; v.f = f;
    unsigned int u = v.u;
    unsigned int r = (u + 0x7FFFu + ((u >> 16) & 1u)) >> 16;
    return (unsigned short)r;
}

// ---------------------------------------------------------------------------
// Prep kernel: border-zero + X transpose only. W is consumed directly by the
// main kernel now (R1 post-mortem: the fused wprep section was latency-bound
// at 2.2 TB/s / 5% VALUBusy -- 72 strided gathers/thread with no ILP).
// 2048 blocks x 256 = 8 blocks/CU x 4 waves = 8 waves/SIMD target occupancy.
// Per wave: 2 units x 8 independent dwords loads, no LDS, no barriers.
// ---------------------------------------------------------------------------
__global__ __launch_bounds__(256) void prep_kernel(const float* __restrict__ X,
                                                   unsigned short* __restrict__ xt) {
    const int id  = blockIdx.x;
    const int tid = threadIdx.x;

    // ---- border zero: 260 x 4KB pixel blocks, handled by blocks 0..259 ----
    if (id < 260) {
        int h1, w1;
        if (id < 66)       { h1 = 0;  w1 = id; }
        else if (id < 132) { h1 = 65; w1 = id - 66; }
        else { int r = id - 132; h1 = (r >> 1) + 1; w1 = (r & 1) ? 65 : 0; }
        ((uint4*)(xt + (size_t)(h1 * HPAD + w1) * 2048))[tid] = uint4{0u, 0u, 0u, 0u};
    }

    // ---- transpose X[b][c][h][w] fp32 -> xt[(h+1)][(w+1)][b][c] bf16 ----
    const int w   = tid >> 2;        // 0..63
    const int cg8 = (tid & 3) * 8;   // channel group base
#pragma unroll
    for (int u = 0; u < 2; ++u) {
        const int unit = id * 2 + u;            // 0..4095
        const int h = unit >> 6, b = unit & 63;
        const float* xb = X + (((size_t)b * CIN + cg8) * HOUT + h) * WOUT + w;
        unsigned short v[8];
#pragma unroll
        for (int j = 0; j < 8; ++j)
            v[j] = f2bf(xb[(size_t)j * HOUT * WOUT]);
        uint4 pack;
        pack.x = (unsigned)v[0] | ((unsigned)v[1] << 16);
        pack.y = (unsigned)v[2] | ((unsigned)v[3] << 16);
        pack.z = (unsigned)v[4] | ((unsigned)v[5] << 16);
        pack.w = (unsigned)v[6] | ((unsigned)v[7] << 16);
        *(uint4*)(xt + (size_t)((h + 1) * HPAD + (w + 1)) * 2048 + b * CIN + cg8) = pack;
    }
}

// ---------------------------------------------------------------------------
// Main kernel. Block = 16 consecutive sites x 16 batches (quarter). Grid 1024.
// The 4 batch-quarter blocks of a site-group get ids == lo (mod 8) within a
// 32-id window -> same XCD -> Wg HBM-fetched once, 3 L2 hits.
//
// B fragments now gathered DIRECTLY from Wg fp32 (no wt intermediate):
//   lane(q,n), tap t needs Wg[s][(8q+j)*9+t][n], j=0..7. Per load instruction
//   the 64 lanes cover 4 full 64B lines (16 consecutive n-dwords each) --
//   same line efficiency the old wprep had, but hidden under MFMA + A-loads.
// bsum is computed inline: fp32 sum of the lane's 72 loads, shfl-reduced over
// q -> identical numerics to the old wprep bsum.
// ---------------------------------------------------------------------------
__global__ __launch_bounds__(256, 4) void varconv_kernel(const unsigned short* __restrict__ xt,
                                                         const float* __restrict__ Wg,
                                                         const float* __restrict__ bias,
                                                         float* __restrict__ out) {
    __shared__ float lds[16 * 324];   // 20.25 KB; 4 blocks/CU -> 81 KB of 160

    int id = blockIdx.x;
    int lo = id & 7;                       // XCD
    int q4 = (id >> 3) & 3;                // batch quarter
    int g  = ((id >> 5) << 3) | lo;        // site-group 0..255
    int s0 = g * 16;
    int y  = s0 >> 6;
    int x0 = s0 & 63;
    int B0 = q4 * 16;

    int lane = threadIdx.x & 63, wv = threadIdx.x >> 6;
    int q = lane >> 4;          // quad
    int n = lane & 15;          // = c_out (B/D), = b-within-tile (A)

#pragma unroll
    for (int i = 0; i < 4; ++i) {
        int sl = wv * 4 + i;
        int s  = s0 + sl;
        int x  = x0 + sl;

        // --- A fragments first (9 contiguous-1KB-per-wave loads, in flight
        //     early so they cover the B-gather latency) ---
        const unsigned short* ab = xt + (size_t)(B0 + n) * CIN + q * 8;
        short8 af[9];
#pragma unroll
        for (int t = 0; t < 9; ++t) {
            const int cy = t / 3, cx = t % 3;
            af[t] = *(const short8*)(ab + (size_t)((y + cy) * HPAD + (x + cx)) * 2048);
        }

        // --- B fragments: direct gather from Wg, 3 tap-groups of 3 to bound
        //     VGPR (24 fp32 in flight per group; peak ~110 total) ---
        const float* wb = Wg + (size_t)s * (KTOT * COUT) + n;
        float csum = 0.f;
        short8 bf[9];
#pragma unroll
        for (int tg = 0; tg < 3; ++tg) {
            float wreg[3][8];
#pragma unroll
            for (int tt = 0; tt < 3; ++tt)
#pragma unroll
                for (int j = 0; j < 8; ++j)
                    wreg[tt][j] = wb[(size_t)((8 * q + j) * 9 + (tg * 3 + tt)) * COUT];
#pragma unroll
            for (int tt = 0; tt < 3; ++tt) {
                unsigned short hh[8];
#pragma unroll
                for (int j = 0; j < 8; ++j) { csum += wreg[tt][j]; hh[j] = f2bf(wreg[tt][j]); }
                union { uint4 u; short8 s8; } cv;
                cv.u.x = (unsigned)hh[0] | ((unsigned)hh[1] << 16);
                cv.u.y = (unsigned)hh[2] | ((unsigned)hh[3] << 16);
                cv.u.z = (unsigned)hh[4] | ((unsigned)hh[5] << 16);
                cv.u.w = (unsigned)hh[6] | ((unsigned)hh[7] << 16);
                bf[tg * 3 + tt] = cv.s8;
            }
        }

        // colsum over q (4 lane groups) -> every lane holds colsum for its n
        csum += __shfl_xor(csum, 16, 64);
        csum += __shfl_xor(csum, 32, 64);
        float badd = bias[s] * csum;

        floatx4 acc = {0.f, 0.f, 0.f, 0.f};
#pragma unroll
        for (int t = 0; t < 9; ++t)
            acc = __builtin_amdgcn_mfma_f32_16x16x32_bf16(af[t], bf[t], acc, 0, 0, 0);

        // D: col = n = c_out, row(b local) = 4q+r. Slot-XOR for conflict-free b128.
        int slot = q ^ (n & 3);
        floatx4 v = {acc[0] + badd, acc[1] + badd, acc[2] + badd, acc[3] + badd};
        *(floatx4*)&lds[n * 324 + sl * 20 + slot * 4] = v;
    }

    __syncthreads();

    // --- epilogue: full-line coalesced writes (4 lanes = one 64B line) ---
    int c   = lane >> 2;     // 0..15
    int slg = lane & 3;      // 0..3
#pragma unroll
    for (int i2 = 0; i2 < 4; ++i2) {
        int ib   = wv * 4 + i2;             // local b 0..15
        int slot = (ib >> 2) ^ (c & 3);
        float o0[4];
#pragma unroll
        for (int e = 0; e < 4; ++e)
            o0[e] = lds[c * 324 + (slg * 4 + e) * 20 + slot * 4 + (ib & 3)];
        floatx4 o = {o0[0], o0[1], o0[2], o0[3]};
        *(floatx4*)(out + ((size_t)((B0 + ib) * COUT + c)) * SLOC + s0 + slg * 4) = o;
    }
}

extern "C" void kernel_launch(void* const* d_in, const int* in_sizes, int n_in,
                              void* d_out, int out_size, void* d_ws, size_t ws_size,
                              hipStream_t stream) {
    const float* X    = (const float*)d_in[0];   // [64][32][64][64] fp32
    const float* Wg   = (const float*)d_in[1];   // [4096][288][16] fp32
    const float* bias = (const float*)d_in[2];   // [4096] fp32
    float* out = (float*)d_out;                  // [64][16][4096] fp32

    // Workspace: xt only now: 66*66*64*32*2 = 17,842,176 B
    unsigned short* xt = (unsigned short*)d_ws;

    prep_kernel<<<2048, 256, 0, stream>>>(X, xt);
    varconv_kernel<<<1024, 256, 0, stream>>>(xt, Wg, bias, out);
}

// Round 3
// 170.195 us; speedup vs baseline: 1.0673x; 1.0673x over previous
//
#include <hip/hip_runtime.h>
#include <stdint.h>
#include <stddef.h>

// Problem constants
#define HOUT 64
#define WOUT 64
#define CIN  32
#define COUT 16
#define BATCH 64
#define SLOC 4096          // HOUT*WOUT
#define KTOT 288           // CIN*9
#define HPAD 66            // 64 + 2 pad
#define WR_STRIDE 296      // ushorts per n-row in LDS W tile: 9*32 + 8 pad
// Padded-X pixel block = BATCH*CIN bf16 = 2048 ushorts = 4096 bytes

typedef __attribute__((ext_vector_type(8))) short  short8;   // 8 bf16 (4 VGPRs)
typedef __attribute__((ext_vector_type(4))) float  floatx4;  // MFMA acc / float4

// fp32 -> bf16 round-to-nearest-even (bit pattern)
static __device__ __forceinline__ unsigned short f2bf(float f) {
    union { float f; unsigned int u; } v; v.f = f;
    unsigned int u = v.u;
    unsigned int r = (u + 0x7FFFu + ((u >> 16) & 1u)) >> 16;
    return (unsigned short)r;
}

// ---------------------------------------------------------------------------
// Prep kernel: border-zero + X transpose. 2048 blocks x 256 threads.
// ---------------------------------------------------------------------------
__global__ __launch_bounds__(256) void prep_kernel(const float* __restrict__ X,
                                                   unsigned short* __restrict__ xt) {
    const int id  = blockIdx.x;
    const int tid = threadIdx.x;

    // ---- border zero: 260 x 4KB pixel blocks, handled by blocks 0..259 ----
    if (id < 260) {
        int h1, w1;
        if (id < 66)       { h1 = 0;  w1 = id; }
        else if (id < 132) { h1 = 65; w1 = id - 66; }
        else { int r = id - 132; h1 = (r >> 1) + 1; w1 = (r & 1) ? 65 : 0; }
        ((uint4*)(xt + (size_t)(h1 * HPAD + w1) * 2048))[tid] = uint4{0u, 0u, 0u, 0u};
    }

    // ---- transpose X[b][c][h][w] fp32 -> xt[(h+1)][(w+1)][b][c] bf16 ----
    const int w   = tid >> 2;        // 0..63
    const int cg8 = (tid & 3) * 8;   // channel group base
#pragma unroll
    for (int u = 0; u < 2; ++u) {
        const int unit = id * 2 + u;            // 0..4095
        const int h = unit >> 6, b = unit & 63;
        const float* xb = X + (((size_t)b * CIN + cg8) * HOUT + h) * WOUT + w;
        unsigned short v[8];
#pragma unroll
        for (int j = 0; j < 8; ++j)
            v[j] = f2bf(xb[(size_t)j * HOUT * WOUT]);
        uint4 pack;
        pack.x = (unsigned)v[0] | ((unsigned)v[1] << 16);
        pack.y = (unsigned)v[2] | ((unsigned)v[3] << 16);
        pack.z = (unsigned)v[4] | ((unsigned)v[5] << 16);
        pack.w = (unsigned)v[6] | ((unsigned)v[7] << 16);
        *(uint4*)(xt + (size_t)((h + 1) * HPAD + (w + 1)) * 2048 + b * CIN + cg8) = pack;
    }
}

// ---------------------------------------------------------------------------
// Main kernel. Block = 8 consecutive sites x ALL 64 batches. Grid 512 x 256
// (2 blocks/CU). Wave = batch quarter; all 4 waves consume the same staged
// site, so W is HBM-read exactly once, contiguously:
//   stage: 1152 uint4 / 256 thr (perfect dwordx4 coalescing), f2bf during
//          the LDS write into W_R[n][tap][c] bf16 (+pad) -- the B-fragment
//          becomes ONE ds_read_b128 per tap (R2 failure: 8 scalar global
//          gathers per tap).
//   bsum : fp32 partials accumulated during staging (thread's 4 n-columns
//          are fixed), shfl-reduced within wave, combined across 4 waves
//          via a 512B LDS buffer. Same numerics as before.
//   epilogue: lane holds 8 CONSECUTIVE s per (b,c) -> direct 2x dwordx4
//          stores, no LDS transpose (R1 showed no write amplification).
// ---------------------------------------------------------------------------
__global__ __launch_bounds__(256, 2) void varconv_kernel(const unsigned short* __restrict__ xt,
                                                         const float* __restrict__ Wg,
                                                         const float* __restrict__ bias,
                                                         float* __restrict__ out) {
    __shared__ unsigned short wr[2][16 * WR_STRIDE];   // 2 x 9.25 KB bf16 W tile
    __shared__ float cs[2][4][16];                     // per-wave colsum partials

    const int id  = blockIdx.x;        // 0..511
    const int s0  = id * 8;
    const int y   = s0 >> 6;
    const int x0  = s0 & 63;
    const int tid = threadIdx.x;
    const int lane = tid & 63, wv = tid >> 6;
    const int q = lane >> 4;           // channel octet for A/B frags
    const int n = lane & 15;           // c_out (B/D); batch-in-quarter (A)
    const int B0 = wv * 16;
    const int nst = (tid & 3) * 4;     // staging: this thread's n-column base

    floatx4 acc[8];
#pragma unroll
    for (int i = 0; i < 8; ++i) acc[i] = floatx4{0.f, 0.f, 0.f, 0.f};

    // ---- staging: site s -> wr[buf], colsum partials -> cs[buf] ----
#define STAGE(S, BUF)                                                          \
    {                                                                          \
        const uint4* wsrc = (const uint4*)(Wg + (size_t)(S) * (KTOT * COUT));  \
        float c0 = 0.f, c1 = 0.f, c2 = 0.f, c3 = 0.f;                          \
        _Pragma("unroll")                                                      \
        for (int it = 0; it < 5; ++it) {                                       \
            int idx = tid + it * 256;                                          \
            if (idx < 1152) {                                                  \
                uint4 v = wsrc[idx];                                           \
                int k = idx >> 2;                                              \
                int c = (unsigned)k / 9u;                                      \
                int t = k - c * 9;                                             \
                unsigned short* dst = &wr[BUF][t * 32 + c];                    \
                union { unsigned int u; float f; } a0, a1, a2, a3;             \
                a0.u = v.x; a1.u = v.y; a2.u = v.z; a3.u = v.w;                \
                dst[(size_t)(nst + 0) * WR_STRIDE] = f2bf(a0.f); c0 += a0.f;   \
                dst[(size_t)(nst + 1) * WR_STRIDE] = f2bf(a1.f); c1 += a1.f;   \
                dst[(size_t)(nst + 2) * WR_STRIDE] = f2bf(a2.f); c2 += a2.f;   \
                dst[(size_t)(nst + 3) * WR_STRIDE] = f2bf(a3.f); c3 += a3.f;   \
            }                                                                  \
        }                                                                      \
        c0 += __shfl_xor(c0, 4, 64);  c1 += __shfl_xor(c1, 4, 64);             \
        c2 += __shfl_xor(c2, 4, 64);  c3 += __shfl_xor(c3, 4, 64);             \
        c0 += __shfl_xor(c0, 8, 64);  c1 += __shfl_xor(c1, 8, 64);             \
        c2 += __shfl_xor(c2, 8, 64);  c3 += __shfl_xor(c3, 8, 64);             \
        c0 += __shfl_xor(c0, 16, 64); c1 += __shfl_xor(c1, 16, 64);            \
        c2 += __shfl_xor(c2, 16, 64); c3 += __shfl_xor(c3, 16, 64);            \
        c0 += __shfl_xor(c0, 32, 64); c1 += __shfl_xor(c1, 32, 64);            \
        c2 += __shfl_xor(c2, 32, 64); c3 += __shfl_xor(c3, 32, 64);            \
        if (lane < 4) {                                                        \
            cs[BUF][wv][lane * 4 + 0] = c0;                                    \
            cs[BUF][wv][lane * 4 + 1] = c1;                                    \
            cs[BUF][wv][lane * 4 + 2] = c2;                                    \
            cs[BUF][wv][lane * 4 + 3] = c3;                                    \
        }                                                                      \
    }

    // ---- compute site-local index i from wr[buf] ----
#define COMPUTE(I, BUF)                                                        \
    {                                                                          \
        const int x = x0 + (I);                                                \
        short8 af[9], bf[9];                                                   \
        _Pragma("unroll")                                                      \
        for (int t = 0; t < 9; ++t) {                                          \
            const int cy = t / 3, cx = t % 3;                                  \
            af[t] = *(const short8*)(xt +                                      \
                (size_t)((y + cy) * HPAD + (x + cx)) * 2048 + (B0 + n) * CIN + q * 8); \
        }                                                                      \
        _Pragma("unroll")                                                      \
        for (int t = 0; t < 9; ++t)                                            \
            bf[t] = *(const short8*)&wr[BUF][n * WR_STRIDE + t * 32 + q * 8];  \
        float badd = bias[s0 + (I)] *                                          \
            (cs[BUF][0][n] + cs[BUF][1][n] + cs[BUF][2][n] + cs[BUF][3][n]);   \
        _Pragma("unroll")                                                      \
        for (int t = 0; t < 9; ++t)                                            \
            acc[I] = __builtin_amdgcn_mfma_f32_16x16x32_bf16(af[t], bf[t], acc[I], 0, 0, 0); \
        acc[I][0] += badd; acc[I][1] += badd;                                  \
        acc[I][2] += badd; acc[I][3] += badd;                                  \
    }

    STAGE(s0, 0);
    __syncthreads();
#pragma unroll
    for (int i = 0; i < 8; ++i) {
        const int buf = i & 1;
        if (i < 7) STAGE(s0 + i + 1, buf ^ 1);
        COMPUTE(i, buf);
        __syncthreads();
    }

    // ---- epilogue: lane (q,n) holds D rows b=B0+4q+r, col c=n, 8 consec s ----
#pragma unroll
    for (int r = 0; r < 4; ++r) {
        const int b = B0 + 4 * q + r;
        float* dst = out + ((size_t)(b * COUT + n)) * SLOC + s0;
        floatx4 lo = {acc[0][r], acc[1][r], acc[2][r], acc[3][r]};
        floatx4 hi = {acc[4][r], acc[5][r], acc[6][r], acc[7][r]};
        *(floatx4*)dst       = lo;
        *(floatx4*)(dst + 4) = hi;
    }
#undef STAGE
#undef COMPUTE
}

extern "C" void kernel_launch(void* const* d_in, const int* in_sizes, int n_in,
                              void* d_out, int out_size, void* d_ws, size_t ws_size,
                              hipStream_t stream) {
    const float* X    = (const float*)d_in[0];   // [64][32][64][64] fp32
    const float* Wg   = (const float*)d_in[1];   // [4096][288][16] fp32
    const float* bias = (const float*)d_in[2];   // [4096] fp32
    float* out = (float*)d_out;                  // [64][16][4096] fp32

    // Workspace: xt only: 66*66*64*32*2 = 17,842,176 B
    unsigned short* xt = (unsigned short*)d_ws;

    prep_kernel<<<2048, 256, 0, stream>>>(X, xt);
    varconv_kernel<<<512, 256, 0, stream>>>(xt, Wg, bias, out);
}

// Round 4
// 165.359 us; speedup vs baseline: 1.0986x; 1.0292x over previous
//
#include <hip/hip_runtime.h>
#include <stdint.h>
#include <stddef.h>

// Problem constants
#define HOUT 64
#define WOUT 64
#define CIN  32
#define COUT 16
#define SLOC 4096          // HOUT*WOUT
#define KTOT 288           // CIN*9
#define HPAD 66            // 64 + 2 pad
#define WPAD 148           // dwords per n-row of LDS W tile (9*16=144 + 4 pad)
// Padded-X pixel block = BATCH*CIN bf16 = 2048 ushorts = 4096 bytes

typedef __attribute__((ext_vector_type(8))) short  short8;   // 8 bf16 (4 VGPRs)
typedef __attribute__((ext_vector_type(4))) float  floatx4;  // MFMA acc / float4

// fp32 -> bf16 round-to-nearest-even (bit pattern)
static __device__ __forceinline__ unsigned short f2bf(float f) {
    union { float f; unsigned int u; } v; v.f = f;
    unsigned int u = v.u;
    unsigned int r = (u + 0x7FFFu + ((u >> 16) & 1u)) >> 16;
    return (unsigned short)r;
}

// ---------------------------------------------------------------------------
// Prep kernel: border-zero + X transpose. 2048 blocks x 256 threads.
// ---------------------------------------------------------------------------
__global__ __launch_bounds__(256) void prep_kernel(const float* __restrict__ X,
                                                   unsigned short* __restrict__ xt) {
    const int id  = blockIdx.x;
    const int tid = threadIdx.x;

    // ---- border zero: 260 x 4KB pixel blocks, handled by blocks 0..259 ----
    if (id < 260) {
        int h1, w1;
        if (id < 66)       { h1 = 0;  w1 = id; }
        else if (id < 132) { h1 = 65; w1 = id - 66; }
        else { int r = id - 132; h1 = (r >> 1) + 1; w1 = (r & 1) ? 65 : 0; }
        ((uint4*)(xt + (size_t)(h1 * HPAD + w1) * 2048))[tid] = uint4{0u, 0u, 0u, 0u};
    }

    // ---- transpose X[b][c][h][w] fp32 -> xt[(h+1)][(w+1)][b][c] bf16 ----
    const int w   = tid >> 2;        // 0..63
    const int cg8 = (tid & 3) * 8;   // channel group base
#pragma unroll
    for (int u = 0; u < 2; ++u) {
        const int unit = id * 2 + u;            // 0..4095
        const int h = unit >> 6, b = unit & 63;
        const float* xb = X + (((size_t)b * CIN + cg8) * HOUT + h) * WOUT + w;
        unsigned short v[8];
#pragma unroll
        for (int j = 0; j < 8; ++j)
            v[j] = f2bf(xb[(size_t)j * HOUT * WOUT]);
        uint4 pack;
        pack.x = (unsigned)v[0] | ((unsigned)v[1] << 16);
        pack.y = (unsigned)v[2] | ((unsigned)v[3] << 16);
        pack.z = (unsigned)v[4] | ((unsigned)v[5] << 16);
        pack.w = (unsigned)v[6] | ((unsigned)v[7] << 16);
        *(uint4*)(xt + (size_t)((h + 1) * HPAD + (w + 1)) * 2048 + b * CIN + cg8) = pack;
    }
}

// ---------------------------------------------------------------------------
// Main kernel. Block = 8 consecutive sites x ALL 64 batches, 512 threads
// (8 waves). Grid 512 -> 2 blocks/CU x 8 waves = 16 waves/CU (R3 had 8).
// Wave (q4 = wv&3, sh = wv>>2): computes sites s0+4sh .. s0+4sh+3 for batch
// quarter q4. Each 4-wave half stages one site per step into its dbuf slice.
//
// LDS W layout (R3 bank-conflict fix): dword L(n,t,cp) = n*148 + t*16 + cp,
// where cp = c/2 and the dword packs bf16(W[2cp*9+t][n]) | bf16(W[(2cp+1)*9+t][n])<<16.
// Stage task tau = ng + 4*cp + 64*t  =>  t is CONSTANT per wave-instruction:
//   write bank = (cp + 16*(ng&1) + const) mod 32 -> 16 distinct cp's mod 16,
//   ng pairs are the free 2-way => ZERO write conflicts (was ~18-way u16 scatter).
// Read: ds_read_b128 at n*148 + t*16 + 4q -> (20n+4q) mod 32 tiles all banks
//   evenly at the b128 minimum (8 dwords/bank).
// ---------------------------------------------------------------------------
__global__ __launch_bounds__(512, 4) void varconv_kernel(const unsigned short* __restrict__ xt,
                                                         const float* __restrict__ Wg,
                                                         const float* __restrict__ bias,
                                                         float* __restrict__ out) {
    __shared__ __align__(16) unsigned int wru[2][2][16 * WPAD];  // [dbuf][half] 37.9 KB
    __shared__ float cs[2][2][4][16];                            // colsum partials

    const int id   = blockIdx.x;        // 0..511
    const int s0   = id * 8;
    const int y    = s0 >> 6;
    const int x0   = s0 & 63;
    const int tid  = threadIdx.x;
    const int lane = tid & 63;
    const int wv   = tid >> 6;          // 0..7
    const int q4   = wv & 3;            // batch quarter
    const int sh   = wv >> 2;           // site half (0: s0+0..3, 1: s0+4..7)
    const int gtid = q4 * 64 + lane;    // 0..255 within staging half-group
    const int q    = lane >> 4;         // channel octet
    const int n    = lane & 15;         // c_out (B/D); batch-in-quarter (A)
    const int B0   = q4 * 16;

    floatx4 acc[4];
#pragma unroll
    for (int i = 0; i < 4; ++i) acc[i] = floatx4{0.f, 0.f, 0.f, 0.f};

    // stage site s0+4*sh+P into wru[BUF][sh]; colsum partials into cs[BUF][sh]
    auto stage = [&](int P, int BUF) {
        const int S = s0 + 4 * sh + P;
        const uint4* wsrc = (const uint4*)(Wg + (size_t)S * (KTOT * COUT));
        unsigned int* wb = &wru[BUF][sh][0];
        float cacc[4] = {0.f, 0.f, 0.f, 0.f};
#pragma unroll
        for (int it = 0; it < 3; ++it) {
            const int tau = gtid + it * 256;            // 576 tasks / 256 threads
            if (tau < 576) {
                const int ng = tau & 3;                 // n-quad (constant per thread)
                const int cp = (tau >> 2) & 15;         // c-pair
                const int t  = tau >> 6;                // tap (constant per wave-instr)
                const int kA = 18 * cp + t;             // row c=2cp ; kB = kA+9 (c=2cp+1)
                union { uint4 u; float f[4]; } fA, fB;
                fA.u = wsrc[kA * 4 + ng];
                fB.u = wsrc[(kA + 9) * 4 + ng];
#pragma unroll
                for (int m = 0; m < 4; ++m) {
                    cacc[m] += fA.f[m] + fB.f[m];
                    wb[(4 * ng + m) * WPAD + t * 16 + cp] =
                        (unsigned)f2bf(fA.f[m]) | ((unsigned)f2bf(fB.f[m]) << 16);
                }
            }
        }
        // reduce cacc over the 16 lanes sharing ng within this wave, then
        // combine the half-group's 4 waves via cs.
#pragma unroll
        for (int m = 0; m < 4; ++m) {
            cacc[m] += __shfl_xor(cacc[m], 4, 64);
            cacc[m] += __shfl_xor(cacc[m], 8, 64);
            cacc[m] += __shfl_xor(cacc[m], 16, 64);
            cacc[m] += __shfl_xor(cacc[m], 32, 64);
        }
        if (lane < 4) {                 // lane == its ng; holds n = 4*lane+m
#pragma unroll
            for (int m = 0; m < 4; ++m)
                cs[BUF][sh][q4][4 * lane + m] = cacc[m];
        }
    };

    auto compute = [&](int P, int BUF, floatx4& a) {
        const int sl = 4 * sh + P;
        const int S  = s0 + sl;
        const int x  = x0 + sl;
        short8 af[9], bf[9];
#pragma unroll
        for (int t = 0; t < 9; ++t) {
            const int cy = t / 3, cx = t % 3;
            af[t] = *(const short8*)(xt + (size_t)((y + cy) * HPAD + (x + cx)) * 2048
                                        + (B0 + n) * CIN + q * 8);
        }
#pragma unroll
        for (int t = 0; t < 9; ++t)
            bf[t] = *(const short8*)&wru[BUF][sh][n * WPAD + t * 16 + 4 * q];
        const float badd = bias[S] * (cs[BUF][sh][0][n] + cs[BUF][sh][1][n]
                                    + cs[BUF][sh][2][n] + cs[BUF][sh][3][n]);
#pragma unroll
        for (int t = 0; t < 9; ++t)
            a = __builtin_amdgcn_mfma_f32_16x16x32_bf16(af[t], bf[t], a, 0, 0, 0);
        a[0] += badd; a[1] += badd; a[2] += badd; a[3] += badd;
    };

    stage(0, 0);
    __syncthreads();
#pragma unroll
    for (int p = 0; p < 4; ++p) {
        const int buf = p & 1;
        if (p < 3) stage(p + 1, buf ^ 1);
        compute(p, buf, acc[p]);
        __syncthreads();
    }

    // ---- epilogue: lane (q,n) holds rows b=B0+4q+r, col c=n, 4 consec s ----
#pragma unroll
    for (int r = 0; r < 4; ++r) {
        const int b = B0 + 4 * q + r;
        float* dst = out + ((size_t)(b * COUT + n)) * SLOC + s0 + 4 * sh;
        *(floatx4*)dst = floatx4{acc[0][r], acc[1][r], acc[2][r], acc[3][r]};
    }
}

extern "C" void kernel_launch(void* const* d_in, const int* in_sizes, int n_in,
                              void* d_out, int out_size, void* d_ws, size_t ws_size,
                              hipStream_t stream) {
    const float* X    = (const float*)d_in[0];   // [64][32][64][64] fp32
    const float* Wg   = (const float*)d_in[1];   // [4096][288][16] fp32
    const float* bias = (const float*)d_in[2];   // [4096] fp32
    float* out = (float*)d_out;                  // [64][16][4096] fp32

    // Workspace: xt only: 66*66*64*32*2 = 17,842,176 B
    unsigned short* xt = (unsigned short*)d_ws;

    prep_kernel<<<2048, 256, 0, stream>>>(X, xt);
    varconv_kernel<<<512, 512, 0, stream>>>(xt, Wg, bias, out);
}

// Round 5
// 163.260 us; speedup vs baseline: 1.1127x; 1.0129x over previous
//
#include <hip/hip_runtime.h>
#include <stdint.h>
#include <stddef.h>

// Problem constants
#define HOUT 64
#define WOUT 64
#define CIN  32
#define COUT 16
#define SLOC 4096          // HOUT*WOUT
#define KTOT 288           // CIN*9
#define HPAD 66            // 64 + 2 pad
#define WPAD 148           // dwords per n-row of LDS W tile (9*16=144 + 4 pad)
// Padded-X pixel block = BATCH*CIN bf16 = 2048 ushorts = 4096 bytes

typedef __attribute__((ext_vector_type(8))) short  short8;   // 8 bf16 (4 VGPRs)
typedef __attribute__((ext_vector_type(4))) float  floatx4;  // MFMA acc / float4
typedef __attribute__((ext_vector_type(2))) float  floatx2;

// fp32 -> bf16 round-to-nearest-even (bit pattern)
static __device__ __forceinline__ unsigned short f2bf(float f) {
    union { float f; unsigned int u; } v; v.f = f;
    unsigned int u = v.u;
    unsigned int r = (u + 0x7FFFu + ((u >> 16) & 1u)) >> 16;
    return (unsigned short)r;
}

// ---------------------------------------------------------------------------
// Prep kernel: border-zero + X transpose. 2048 blocks x 256 threads.
// ---------------------------------------------------------------------------
__global__ __launch_bounds__(256) void prep_kernel(const float* __restrict__ X,
                                                   unsigned short* __restrict__ xt) {
    const int id  = blockIdx.x;
    const int tid = threadIdx.x;

    // ---- border zero: 260 x 4KB pixel blocks, handled by blocks 0..259 ----
    if (id < 260) {
        int h1, w1;
        if (id < 66)       { h1 = 0;  w1 = id; }
        else if (id < 132) { h1 = 65; w1 = id - 66; }
        else { int r = id - 132; h1 = (r >> 1) + 1; w1 = (r & 1) ? 65 : 0; }
        ((uint4*)(xt + (size_t)(h1 * HPAD + w1) * 2048))[tid] = uint4{0u, 0u, 0u, 0u};
    }

    // ---- transpose X[b][c][h][w] fp32 -> xt[(h+1)][(w+1)][b][c] bf16 ----
    const int w   = tid >> 2;        // 0..63
    const int cg8 = (tid & 3) * 8;   // channel group base
#pragma unroll
    for (int u = 0; u < 2; ++u) {
        const int unit = id * 2 + u;            // 0..4095
        const int h = unit >> 6, b = unit & 63;
        const float* xb = X + (((size_t)b * CIN + cg8) * HOUT + h) * WOUT + w;
        unsigned short v[8];
#pragma unroll
        for (int j = 0; j < 8; ++j)
            v[j] = f2bf(xb[(size_t)j * HOUT * WOUT]);
        uint4 pack;
        pack.x = (unsigned)v[0] | ((unsigned)v[1] << 16);
        pack.y = (unsigned)v[2] | ((unsigned)v[3] << 16);
        pack.z = (unsigned)v[4] | ((unsigned)v[5] << 16);
        pack.w = (unsigned)v[6] | ((unsigned)v[7] << 16);
        *(uint4*)(xt + (size_t)((h + 1) * HPAD + (w + 1)) * 2048 + b * CIN + cg8) = pack;
    }
}

// ---------------------------------------------------------------------------
// Main kernel (R5): block = 2 consecutive sites x ALL 64 batches, 256 threads
// (4 waves = 4 batch quarters). Grid 2048 -> 8 blocks/CU, 32 waves/CU.
// ONE barrier per block: stage both sites -> sync -> compute both -> store.
// R4 post-mortem: 2 blocks/CU + 5 barriers/block = serial latency chain
// (VALUBusy 7.9%). Here inter-block TLP (8 blocks/CU) hides HBM latency.
//
// XCD swizzle: sg = (id&7)*256 + (id>>3) -> each XCD owns a contiguous
// 512-site span; neighboring blocks (ids 8 apart) share out-lines in the
// same L2 -> full-line writebacks (R4 WRITE was 28MB vs 16.8 ideal).
//
// LDS W layout (R4's conflict-free scheme, per site): dword L(n,t,cp) =
// n*WPAD + t*16 + cp packs bf16(W[2cp*9+t][n]) | bf16(W[(2cp+1)*9+t][n])<<16.
// Task tau: 64-aligned chunks have constant (site,t) -> per wave-instr the
// write covers 16 cp x {ng even/odd -> +-16 banks} = 2 lanes/bank (free).
// Read ds_read_b128 at n*WPAD + t*16 + 4q: 8 dwords/bank (b128 minimum).
// ---------------------------------------------------------------------------
__global__ __launch_bounds__(256, 8) void varconv_kernel(const unsigned short* __restrict__ xt,
                                                         const float* __restrict__ Wg,
                                                         const float* __restrict__ bias,
                                                         float* __restrict__ out) {
    __shared__ __align__(16) unsigned int wru[2][16 * WPAD];  // 2 sites, 18.5 KB
    __shared__ float cs[2][4][16];                            // colsum partials

    const int id   = blockIdx.x;               // 0..2047
    const int sg   = (id & 7) * 256 + (id >> 3);   // site-group, XCD-contiguous
    const int s0   = sg * 2;
    const int y    = s0 >> 6;
    const int x0   = s0 & 63;                  // even; x0+3 <= 65 within pad
    const int tid  = threadIdx.x;
    const int lane = tid & 63;
    const int wv   = tid >> 6;                 // batch quarter
    const int q    = lane >> 4;                // channel octet
    const int n    = lane & 15;                // c_out (B/D); batch-in-quarter (A)
    const int B0   = wv * 16;

    // ---- stage BOTH sites (36 KB contiguous Wg -> LDS bf16 + colsum) ----
    const uint4* wsrc = (const uint4*)(Wg + (size_t)s0 * (KTOT * COUT));
    float cacc0[4] = {0.f, 0.f, 0.f, 0.f};
    float cacc1[4] = {0.f, 0.f, 0.f, 0.f};

    // one task: t2 in [0,576) of site SITE: ng=t2&3, cp=(t2>>2)&15, t=t2>>6
#define STTASK(T2, SITE, CACC)                                                 \
    {                                                                          \
        const int ng = (T2) & 3, cp = ((T2) >> 2) & 15, t = (T2) >> 6;         \
        const int kA = 18 * cp + t;                                            \
        union { uint4 u; float f[4]; } fA, fB;                                 \
        fA.u = wsrc[(SITE) * 1152 + kA * 4 + ng];                              \
        fB.u = wsrc[(SITE) * 1152 + (kA + 9) * 4 + ng];                        \
        unsigned int* wb = &wru[SITE][0];                                      \
        _Pragma("unroll")                                                      \
        for (int m = 0; m < 4; ++m) {                                          \
            CACC[m] += fA.f[m] + fB.f[m];                                      \
            wb[(4 * ng + m) * WPAD + t * 16 + cp] =                            \
                (unsigned)f2bf(fA.f[m]) | ((unsigned)f2bf(fB.f[m]) << 16);     \
        }                                                                      \
    }

#pragma unroll
    for (int it = 0; it < 5; ++it) {
        const int tau = tid + it * 256;        // 64-aligned chunks: (site,t) wave-uniform
        if (tau < 576) {
            STTASK(tau, 0, cacc0)
        } else if (tau < 1152) {
            const int t2 = tau - 576;
            STTASK(t2, 1, cacc1)
        }
    }
#undef STTASK

    // reduce colsums over lanes sharing ng (= tid&3) within the wave
#pragma unroll
    for (int m = 0; m < 4; ++m) {
        cacc0[m] += __shfl_xor(cacc0[m], 4, 64);
        cacc1[m] += __shfl_xor(cacc1[m], 4, 64);
        cacc0[m] += __shfl_xor(cacc0[m], 8, 64);
        cacc1[m] += __shfl_xor(cacc1[m], 8, 64);
        cacc0[m] += __shfl_xor(cacc0[m], 16, 64);
        cacc1[m] += __shfl_xor(cacc1[m], 16, 64);
        cacc0[m] += __shfl_xor(cacc0[m], 32, 64);
        cacc1[m] += __shfl_xor(cacc1[m], 32, 64);
    }
    if (lane < 4) {                            // lane == ng; holds n = 4*lane+m
#pragma unroll
        for (int m = 0; m < 4; ++m) {
            cs[0][wv][4 * lane + m] = cacc0[m];
            cs[1][wv][4 * lane + m] = cacc1[m];
        }
    }

    __syncthreads();

    // ---- compute both sites ----
    floatx4 acc[2];
#pragma unroll
    for (int i = 0; i < 2; ++i) acc[i] = floatx4{0.f, 0.f, 0.f, 0.f};

#define COMPUTE(I)                                                             \
    {                                                                          \
        const int x = x0 + (I);                                                \
        short8 af[9], bf[9];                                                   \
        _Pragma("unroll")                                                      \
        for (int t = 0; t < 9; ++t) {                                          \
            const int cy = t / 3, cx = t % 3;                                  \
            af[t] = *(const short8*)(xt + (size_t)((y + cy) * HPAD + (x + cx)) * 2048 \
                                        + (B0 + n) * CIN + q * 8);             \
        }                                                                      \
        _Pragma("unroll")                                                      \
        for (int t = 0; t < 9; ++t)                                            \
            bf[t] = *(const short8*)&wru[I][n * WPAD + t * 16 + 4 * q];        \
        const float badd = bias[s0 + (I)] * (cs[I][0][n] + cs[I][1][n]        \
                                           + cs[I][2][n] + cs[I][3][n]);       \
        _Pragma("unroll")                                                      \
        for (int t = 0; t < 9; ++t)                                            \
            acc[I] = __builtin_amdgcn_mfma_f32_16x16x32_bf16(af[t], bf[t], acc[I], 0, 0, 0); \
        acc[I][0] += badd; acc[I][1] += badd;                                  \
        acc[I][2] += badd; acc[I][3] += badd;                                  \
    }

    COMPUTE(0)
    COMPUTE(1)
#undef COMPUTE

    // ---- epilogue: lane (q,n) holds rows b=B0+4q+r, col c=n, 2 consec s ----
#pragma unroll
    for (int r = 0; r < 4; ++r) {
        const int b = B0 + 4 * q + r;
        float* dst = out + ((size_t)(b * COUT + n)) * SLOC + s0;
        *(floatx2*)dst = floatx2{acc[0][r], acc[1][r]};
    }
}

extern "C" void kernel_launch(void* const* d_in, const int* in_sizes, int n_in,
                              void* d_out, int out_size, void* d_ws, size_t ws_size,
                              hipStream_t stream) {
    const float* X    = (const float*)d_in[0];   // [64][32][64][64] fp32
    const float* Wg   = (const float*)d_in[1];   // [4096][288][16] fp32
    const float* bias = (const float*)d_in[2];   // [4096] fp32
    float* out = (float*)d_out;                  // [64][16][4096] fp32

    // Workspace: xt only: 66*66*64*32*2 = 17,842,176 B
    unsigned short* xt = (unsigned short*)d_ws;

    prep_kernel<<<2048, 256, 0, stream>>>(X, xt);
    varconv_kernel<<<2048, 256, 0, stream>>>(xt, Wg, bias, out);
}

// Round 6
// 155.374 us; speedup vs baseline: 1.1692x; 1.0508x over previous
//
#include <hip/hip_runtime.h>
#include <stdint.h>
#include <stddef.h>

// Problem constants
#define HOUT 64
#define WOUT 64
#define CIN  32
#define COUT 16
#define SLOC 4096          // HOUT*WOUT
#define KTOT 288           // CIN*9
#define HPAD 66            // 64 + 2 pad
#define WPAD 148           // dwords per n-row of LDS W tile (9*16=144 + 4 pad)
// Padded-X pixel block = BATCH*CIN bf16 = 2048 ushorts = 4096 bytes

typedef __attribute__((ext_vector_type(8))) short  short8;   // 8 bf16 (4 VGPRs)
typedef __attribute__((ext_vector_type(4))) float  floatx4;  // MFMA acc / float4
typedef __attribute__((ext_vector_type(2))) float  floatx2;

// fp32 -> bf16 round-to-nearest-even (bit pattern)
static __device__ __forceinline__ unsigned short f2bf(float f) {
    union { float f; unsigned int u; } v; v.f = f;
    unsigned int u = v.u;
    unsigned int r = (u + 0x7FFFu + ((u >> 16) & 1u)) >> 16;
    return (unsigned short)r;
}

// ---------------------------------------------------------------------------
// Prep kernel: border-zero + X transpose. 2048 blocks x 256 threads.
// ---------------------------------------------------------------------------
__global__ __launch_bounds__(256) void prep_kernel(const float* __restrict__ X,
                                                   unsigned short* __restrict__ xt) {
    const int id  = blockIdx.x;
    const int tid = threadIdx.x;

    // ---- border zero: 260 x 4KB pixel blocks, handled by blocks 0..259 ----
    if (id < 260) {
        int h1, w1;
        if (id < 66)       { h1 = 0;  w1 = id; }
        else if (id < 132) { h1 = 65; w1 = id - 66; }
        else { int r = id - 132; h1 = (r >> 1) + 1; w1 = (r & 1) ? 65 : 0; }
        ((uint4*)(xt + (size_t)(h1 * HPAD + w1) * 2048))[tid] = uint4{0u, 0u, 0u, 0u};
    }

    // ---- transpose X[b][c][h][w] fp32 -> xt[(h+1)][(w+1)][b][c] bf16 ----
    const int w   = tid >> 2;        // 0..63
    const int cg8 = (tid & 3) * 8;   // channel group base
#pragma unroll
    for (int u = 0; u < 2; ++u) {
        const int unit = id * 2 + u;            // 0..4095
        const int h = unit >> 6, b = unit & 63;
        const float* xb = X + (((size_t)b * CIN + cg8) * HOUT + h) * WOUT + w;
        unsigned short v[8];
#pragma unroll
        for (int j = 0; j < 8; ++j)
            v[j] = f2bf(xb[(size_t)j * HOUT * WOUT]);
        uint4 pack;
        pack.x = (unsigned)v[0] | ((unsigned)v[1] << 16);
        pack.y = (unsigned)v[2] | ((unsigned)v[3] << 16);
        pack.z = (unsigned)v[4] | ((unsigned)v[5] << 16);
        pack.w = (unsigned)v[6] | ((unsigned)v[7] << 16);
        *(uint4*)(xt + (size_t)((h + 1) * HPAD + (w + 1)) * 2048 + b * CIN + cg8) = pack;
    }
}

// ---------------------------------------------------------------------------
// Main kernel (R6): same decomposition as R5 (block = 2 sites x 64 batches,
// 256 thr, grid 2048, one barrier, conflict-free LDS W layout) but
// restructured for LOAD ILP (R5 post-mortem: VGPR_Count=24 -> compiler
// serialized every load into a dependent round-trip; occupancy was never
// the constraint).
//   phase 1: issue ALL 10 staging dwordx4 into fA[5]/fB[5]   (40 VGPR)
//   phase 2: issue ALL A-fragments; sites share 2/3 tap-cols -> 12 unique
//            loads (af[3][4], 48 VGPR) cover both sites' 18 MFMAs
//   phase 3: one vmcnt drain -> f2bf + LDS scatter + colsum shfl
//   phase 4: barrier -> ds_read_b128 B-frags + MFMA on resident A-regs
// __launch_bounds__(256,4): 128-VGPR cap (est. ~110), 4 blocks/CU.
// ---------------------------------------------------------------------------
__global__ __launch_bounds__(256, 4) void varconv_kernel(const unsigned short* __restrict__ xt,
                                                         const float* __restrict__ Wg,
                                                         const float* __restrict__ bias,
                                                         float* __restrict__ out) {
    __shared__ __align__(16) unsigned int wru[2][16 * WPAD];  // 2 sites, 18.5 KB
    __shared__ float cs[2][4][16];                            // colsum partials

    const int id   = blockIdx.x;                   // 0..2047
    const int sg   = (id & 7) * 256 + (id >> 3);   // site-group, XCD-contiguous
    const int s0   = sg * 2;
    const int y    = s0 >> 6;
    const int x0   = s0 & 63;                      // even; x0+3 <= 65 within pad
    const int tid  = threadIdx.x;
    const int lane = tid & 63;
    const int wv   = tid >> 6;                     // batch quarter
    const int q    = lane >> 4;                    // channel octet
    const int n    = lane & 15;                    // c_out (B/D); batch-in-quarter (A)
    const int B0   = wv * 16;

    // ---- phase 1: issue all staging loads (both sites, 36 KB contiguous) ----
    const uint4* wsrc = (const uint4*)(Wg + (size_t)s0 * (KTOT * COUT));
    uint4 fA[5], fB[5];
#pragma unroll
    for (int it = 0; it < 5; ++it) {
        const int tau  = tid + it * 256;           // 0..1279; 1152 real tasks
        const int tt   = tau < 1152 ? tau : 1151;  // dup-load tail (masked later)
        const int site = tt >= 576;
        const int t2   = tt - 576 * site;
        const int ng = t2 & 3, cp = (t2 >> 2) & 15, t = t2 >> 6;
        const int kA = 18 * cp + t;                // row c=2cp ; +9 -> c=2cp+1
        fA[it] = wsrc[site * 1152 + kA * 4 + ng];
        fB[it] = wsrc[site * 1152 + (kA + 9) * 4 + ng];
    }

    // ---- phase 2: issue all A-fragment loads (12 shared across both sites) ----
    const unsigned short* abase = xt + (size_t)(B0 + n) * CIN + q * 8;
    short8 af[3][4];
#pragma unroll
    for (int cy = 0; cy < 3; ++cy)
#pragma unroll
        for (int cx = 0; cx < 4; ++cx)
            af[cy][cx] = *(const short8*)(abase + (size_t)((y + cy) * HPAD + (x0 + cx)) * 2048);

    // ---- phase 3: convert + conflict-free LDS scatter + colsum ----
    // LDS dword L(n,t,cp) = n*WPAD + t*16 + cp packs bf16(W[2cp*9+t][n]) |
    // bf16(W[(2cp+1)*9+t][n])<<16. Per wave-instr t is constant -> 16 cp's x
    // ng-parity = 2 lanes/bank (free). Explicit site branches keep cacc in
    // registers (no runtime-indexed register arrays -> no scratch).
    float cacc0[4] = {0.f, 0.f, 0.f, 0.f};
    float cacc1[4] = {0.f, 0.f, 0.f, 0.f};
#pragma unroll
    for (int it = 0; it < 5; ++it) {
        const int tau = tid + it * 256;
        if (tau < 1152) {
            union { uint4 u; float f[4]; } a, b;
            a.u = fA[it]; b.u = fB[it];
            if (tau < 576) {
                const int ng = tau & 3, cp = (tau >> 2) & 15, t = tau >> 6;
#pragma unroll
                for (int m = 0; m < 4; ++m) {
                    cacc0[m] += a.f[m] + b.f[m];
                    wru[0][(4 * ng + m) * WPAD + t * 16 + cp] =
                        (unsigned)f2bf(a.f[m]) | ((unsigned)f2bf(b.f[m]) << 16);
                }
            } else {
                const int t2 = tau - 576;
                const int ng = t2 & 3, cp = (t2 >> 2) & 15, t = t2 >> 6;
#pragma unroll
                for (int m = 0; m < 4; ++m) {
                    cacc1[m] += a.f[m] + b.f[m];
                    wru[1][(4 * ng + m) * WPAD + t * 16 + cp] =
                        (unsigned)f2bf(a.f[m]) | ((unsigned)f2bf(b.f[m]) << 16);
                }
            }
        }
    }

    // reduce colsums over lanes sharing ng (= tid&3) within the wave
#pragma unroll
    for (int m = 0; m < 4; ++m) {
        cacc0[m] += __shfl_xor(cacc0[m], 4, 64);
        cacc1[m] += __shfl_xor(cacc1[m], 4, 64);
        cacc0[m] += __shfl_xor(cacc0[m], 8, 64);
        cacc1[m] += __shfl_xor(cacc1[m], 8, 64);
        cacc0[m] += __shfl_xor(cacc0[m], 16, 64);
        cacc1[m] += __shfl_xor(cacc1[m], 16, 64);
        cacc0[m] += __shfl_xor(cacc0[m], 32, 64);
        cacc1[m] += __shfl_xor(cacc1[m], 32, 64);
    }
    if (lane < 4) {                                // lane == ng; holds n = 4*lane+m
#pragma unroll
        for (int m = 0; m < 4; ++m) {
            cs[0][wv][4 * lane + m] = cacc0[m];
            cs[1][wv][4 * lane + m] = cacc1[m];
        }
    }

    __syncthreads();

    // ---- phase 4: B-frags from LDS + 18 MFMAs on resident A-regs ----
    // Read ds_read_b128 at n*WPAD + t*16 + 4q: 8 dwords/bank (b128 minimum).
    floatx4 acc0 = {0.f, 0.f, 0.f, 0.f};
    floatx4 acc1 = {0.f, 0.f, 0.f, 0.f};
    const unsigned int* w0 = &wru[0][n * WPAD + 4 * q];
    const unsigned int* w1 = &wru[1][n * WPAD + 4 * q];
#pragma unroll
    for (int t = 0; t < 9; ++t) {
        const int cy = t / 3, cx = t % 3;
        const short8 b0 = *(const short8*)(w0 + t * 16);
        acc0 = __builtin_amdgcn_mfma_f32_16x16x32_bf16(af[cy][cx], b0, acc0, 0, 0, 0);
        const short8 b1 = *(const short8*)(w1 + t * 16);
        acc1 = __builtin_amdgcn_mfma_f32_16x16x32_bf16(af[cy][cx + 1], b1, acc1, 0, 0, 0);
    }
    const float badd0 = bias[s0] *     (cs[0][0][n] + cs[0][1][n] + cs[0][2][n] + cs[0][3][n]);
    const float badd1 = bias[s0 + 1] * (cs[1][0][n] + cs[1][1][n] + cs[1][2][n] + cs[1][3][n]);

    // ---- epilogue: lane (q,n) holds rows b=B0+4q+r, col c=n, 2 consec s ----
#pragma unroll
    for (int r = 0; r < 4; ++r) {
        const int b = B0 + 4 * q + r;
        float* dst = out + ((size_t)(b * COUT + n)) * SLOC + s0;
        *(floatx2*)dst = floatx2{acc0[r] + badd0, acc1[r] + badd1};
    }
}

extern "C" void kernel_launch(void* const* d_in, const int* in_sizes, int n_in,
                              void* d_out, int out_size, void* d_ws, size_t ws_size,
                              hipStream_t stream) {
    const float* X    = (const float*)d_in[0];   // [64][32][64][64] fp32
    const float* Wg   = (const float*)d_in[1];   // [4096][288][16] fp32
    const float* bias = (const float*)d_in[2];   // [4096] fp32
    float* out = (float*)d_out;                  // [64][16][4096] fp32

    // Workspace: xt only: 66*66*64*32*2 = 17,842,176 B
    unsigned short* xt = (unsigned short*)d_ws;

    prep_kernel<<<2048, 256, 0, stream>>>(X, xt);
    varconv_kernel<<<2048, 256, 0, stream>>>(xt, Wg, bias, out);
}